// Round 11
// baseline (165.592 us; speedup 1.0000x reference)
//
#include <hip/hip_runtime.h>
#include <math.h>

#define CC 128      // channels (FIN=HID=OUT)

typedef unsigned short u16;
typedef short bf16x8 __attribute__((ext_vector_type(8)));
typedef float f32x4 __attribute__((ext_vector_type(4)));

typedef __attribute__((address_space(3))) void lds_t;
typedef const __attribute__((address_space(1))) void gbl_t;

__device__ __forceinline__ u16 f2bf(float f) {
    union { float f; unsigned u; } v; v.f = f;
    unsigned u = v.u;
    return (u16)((u + 0x7FFFu + ((u >> 16) & 1u)) >> 16);   // RNE
}
__device__ __forceinline__ float bf2f(unsigned hi16) {
    union { unsigned u; float f; } v; v.u = hi16 << 16; return v.f;
}
// HW packed f32->bf16 (RNE): 2 values in 1 instruction.
__device__ __forceinline__ unsigned cvt_pk(float lo, float hi) {
    unsigned r;
    asm("v_cvt_pk_bf16_f32 %0, %1, %2" : "=v"(r) : "v"(lo), "v"(hi));
    return r;
}

// Exact-GELU via branch-free A&S 7.1.26 erf (|err| < 1.5e-7).
__device__ __forceinline__ float gelu_f(float y) {
    float xa = fabsf(y) * 0.70710678118654752f;
    float t  = __builtin_amdgcn_rcpf(fmaf(0.3275911f, xa, 1.0f));
    float p  = fmaf(1.061405429f, t, -1.453152027f);
    p = fmaf(p, t, 1.421413741f);
    p = fmaf(p, t, -0.284496736f);
    p = fmaf(p, t, 0.254829592f);
    p *= t;
    float e  = __expf(-xa * xa);
    float er = fmaf(-p, e, 1.0f);
    float s  = copysignf(er, y);
    return 0.5f * y * (1.0f + s);
}

// ---------------- CSR build ----------------

__global__ __launch_bounds__(256) void k_zero_i32(int* __restrict__ p, int n) {
    int i = blockIdx.x * 256 + threadIdx.x;
    if (i < n) p[i] = 0;
}

__global__ __launch_bounds__(256) void k_hist(const int* __restrict__ row, int* __restrict__ cnt, int E) {
    int e = blockIdx.x * 256 + threadIdx.x;
    if (e < E) atomicAdd(&cnt[row[e]], 1);
}

__device__ __forceinline__ int wave_incl_scan(int v) {
    #pragma unroll
    for (int d = 1; d < 64; d <<= 1) {
        int t = __shfl_up(v, d);
        if ((threadIdx.x & 63) >= d) v += t;
    }
    return v;
}

__global__ __launch_bounds__(256) void k_scan_a(const int* __restrict__ cnt, int* __restrict__ bsum, int N) {
    int base = blockIdx.x * 1024 + threadIdx.x * 4;
    int s = 0;
    #pragma unroll
    for (int u = 0; u < 4; ++u) { int i = base + u; if (i < N) s += cnt[i]; }
    #pragma unroll
    for (int d = 32; d > 0; d >>= 1) s += __shfl_down(s, d);
    __shared__ int wsum[4];
    if ((threadIdx.x & 63) == 0) wsum[threadIdx.x >> 6] = s;
    __syncthreads();
    if (threadIdx.x == 0) bsum[blockIdx.x] = wsum[0] + wsum[1] + wsum[2] + wsum[3];
}

__global__ __launch_bounds__(64) void k_scan_b(const int* __restrict__ bsum, int* __restrict__ boff,
                                               int* __restrict__ off, int N, int nb) {
    int carry = 0;
    for (int base = 0; base < nb; base += 64) {
        int t = base + (int)threadIdx.x;
        int v = (t < nb) ? bsum[t] : 0;
        int incl = wave_incl_scan(v);
        if (t < nb) boff[t] = carry + incl - v;
        carry += __shfl(incl, 63);
    }
    if (threadIdx.x == 0) off[N] = carry;
}

__global__ __launch_bounds__(256) void k_scan_c(int* __restrict__ cnt, const int* __restrict__ boff,
                                                int* __restrict__ off, int N) {
    int t = threadIdx.x;
    int base = blockIdx.x * 1024 + t * 4;
    int v[4]; int s = 0;
    #pragma unroll
    for (int u = 0; u < 4; ++u) { int i = base + u; v[u] = (i < N) ? cnt[i] : 0; s += v[u]; }
    int incl = wave_incl_scan(s);
    __shared__ int wsum[4];
    int w = t >> 6, lane = t & 63;
    if (lane == 63) wsum[w] = incl;
    __syncthreads();
    int run = incl - s + boff[blockIdx.x];
    for (int ww = 0; ww < w; ++ww) run += wsum[ww];
    #pragma unroll
    for (int u = 0; u < 4; ++u) {
        int i = base + u;
        if (i < N) { off[i] = run; cnt[i] = 0; }
        run += v[u];
    }
}

__global__ __launch_bounds__(256) void k_fill(const int* __restrict__ row, const int* __restrict__ col,
                                              const float* __restrict__ nrm, const int* __restrict__ off,
                                              int* __restrict__ cur, int2* __restrict__ eg, int E) {
    int e = blockIdx.x * 256 + threadIdx.x;
    if (e < E) {
        int r = row[e];
        int p = off[r] + atomicAdd(&cur[r], 1);
        eg[p] = make_int2(col[e], __float_as_int(nrm[e]));
    }
}

// ---------------- W repack into MFMA B-fragment order ----------------
// W1: standard k-order. W2: k-order permuted by pi(p) = (p&7)*16 + (p>>3), matching the
// channel-permuted layout the fused kernel stores Z in (position p holds channel pi(p)).
__global__ __launch_bounds__(256) void k_wrepack(const float* __restrict__ W1, u16* __restrict__ Wp1,
                                                 const float* __restrict__ W2, u16* __restrict__ Wp2) {
    int i = blockIdx.x * 256 + threadIdx.x;
    if (i < 2 * CC * CC) {
        int is2 = (i >= CC * CC);
        int ii = is2 ? i - CC * CC : i;
        int j = ii & 7, l = (ii >> 3) & 63, s = (ii >> 9) & 3, t = ii >> 11;
        int r = 16 * t + (l & 15);
        int p = s * 32 + ((l >> 4) & 3) * 8 + j;             // fragment k-position 0..127
        if (is2) {
            int k = (p & 7) * 16 + (p >> 3);                 // pi(p)
            Wp2[ii] = f2bf(W2[r * CC + k]);
        } else {
            Wp1[ii] = f2bf(W1[r * CC + p]);
        }
    }
}

// ---------------- K1: GEMM1 + BN1 + GELU1 + GEMM2 (fused) ----------------
// Z stored NODE-MAJOR interleaved: Z[node][batch][128] (permuted channel order within row).
__global__ __launch_bounds__(256) void k_fused_l1(
    const float* __restrict__ X, const u16* __restrict__ Wp1, const u16* __restrict__ Wp2,
    const float* __restrict__ bias, const float* __restrict__ gamma, const float* __restrict__ beta,
    u16* __restrict__ Z, int N)
{
    __shared__ __align__(16) u16 WS[CC * CC];          // 32KB: W1 in pass1, W2 in pass2
    __shared__ __align__(16) unsigned TT[4][16][68];   // per-wave A1 transpose

    const int tid = threadIdx.x;
    const int w = tid >> 6;
    const int l = tid & 63;
    const int g = l >> 4;
    const int c = l & 15;
    const int n8 = blockIdx.x * 32 + w * 8;
    const bool valid = n8 < N;
    const int nbase = valid ? n8 : 0;

    // ---- stage W1 -> LDS (async DMA, 32KB/block) ----
    #pragma unroll
    for (int it = 0; it < 8; ++it) {
        const u16* gsrc = Wp1 + it * 2048 + w * 512 + l * 8;
        u16* ldst = &WS[it * 2048 + w * 512];
        __builtin_amdgcn_global_load_lds((gbl_t*)gsrc, (lds_t*)ldst, 16, 0, 0);
    }

    // ---- A fragments from X (f32), rides under the DMA ----
    const int ab = c >> 3;
    const int an = nbase + (c & 7);
    const float* xbase = X + ((size_t)ab * N + an) * CC + g * 8;
    bf16x8 af[4];
    #pragma unroll
    for (int s = 0; s < 4; ++s) {
        float4 lo = *(const float4*)(xbase + s * 32);
        float4 hi = *(const float4*)(xbase + s * 32 + 4);
        unsigned aw[4];
        aw[0] = cvt_pk(lo.x, lo.y); aw[1] = cvt_pk(lo.z, lo.w);
        aw[2] = cvt_pk(hi.x, hi.y); aw[3] = cvt_pk(hi.z, hi.w);
        af[s] = *(bf16x8*)aw;
    }

    // epilogue params
    float bb[8];
    #pragma unroll
    for (int t = 0; t < 8; ++t) bb[t] = bias[t * 16 + c];
    float gam[4], bet[4];
    #pragma unroll
    for (int r = 0; r < 4; ++r) {
        int p = (4 * g + r) & 7;
        gam[r] = gamma[nbase + p];
        bet[r] = beta[nbase + p];
    }

    __syncthreads();   // W1 staged

    // ---- MFMA pass 1 ----
    f32x4 acc[8];
    #pragma unroll
    for (int t = 0; t < 8; ++t) acc[t] = (f32x4){0.f, 0.f, 0.f, 0.f};
    #pragma unroll
    for (int s = 0; s < 4; ++s) {
        bf16x8 bf[8];
        #pragma unroll
        for (int t = 0; t < 8; ++t)
            bf[t] = *(const bf16x8*)&WS[((t * 4 + s) * 64 + l) * 8];
        #pragma unroll
        for (int t = 0; t < 8; ++t)
            acc[t] = __builtin_amdgcn_mfma_f32_16x16x32_bf16(af[s], bf[t], acc[t], 0, 0, 0);
    }

    __syncthreads();   // all waves done reading W1

    // ---- stage W2 into same LDS; latency hidden under the epilogue ----
    #pragma unroll
    for (int it = 0; it < 8; ++it) {
        const u16* gsrc = Wp2 + it * 2048 + w * 512 + l * 8;
        u16* ldst = &WS[it * 2048 + w * 512];
        __builtin_amdgcn_global_load_lds((gbl_t*)gsrc, (lds_t*)ldst, 16, 0, 0);
    }

    // ---- bias + BN1 stats ----
    float rs[4] = {0.f, 0.f, 0.f, 0.f}, rq[4] = {0.f, 0.f, 0.f, 0.f};
    #pragma unroll
    for (int t = 0; t < 8; ++t)
        #pragma unroll
        for (int r = 0; r < 4; ++r) {
            float h = acc[t][r] + bb[t];
            acc[t][r] = h;
            rs[r] += h;
            rq[r] += h * h;
        }
    #pragma unroll
    for (int d = 1; d < 16; d <<= 1) {
        #pragma unroll
        for (int r = 0; r < 4; ++r) {
            rs[r] += __shfl_xor(rs[r], d);
            rq[r] += __shfl_xor(rq[r], d);
        }
    }
    #pragma unroll
    for (int r = 0; r < 4; ++r) {
        rs[r] += __shfl_xor(rs[r], 32);
        rq[r] += __shfl_xor(rq[r], 32);
    }

    // ---- BN1 + GELU1 ----
    #pragma unroll
    for (int r = 0; r < 4; ++r) {
        float mean = rs[r] * (1.f / 256.f);
        float var  = rq[r] * (1.f / 256.f) - mean * mean;
        float sc = gam[r] * rsqrtf(fmaxf(var, 0.f) + 1e-5f);
        float sh = bet[r] - mean * sc;
        #pragma unroll
        for (int t = 0; t < 8; ++t)
            acc[t][r] = gelu_f(acc[t][r] * sc + sh);
    }

    // ---- A1 -> wave-private LDS tile (permuted pos c*8+t), then A2-fragments ----
    #pragma unroll
    for (int r = 0; r < 4; ++r) {
        unsigned tw[4];
        #pragma unroll
        for (int tt = 0; tt < 4; ++tt)
            tw[tt] = cvt_pk(acc[2 * tt][r], acc[2 * tt + 1][r]);
        *(uint4*)&TT[w][4 * g + r][c * 4] = *(uint4*)tw;
    }
    bf16x8 af2[4];
    #pragma unroll
    for (int s = 0; s < 4; ++s)
        af2[s] = *(const bf16x8*)&TT[w][c][s * 16 + g * 4];

    __syncthreads();   // W2 staged

    // ---- MFMA pass 2 ----
    f32x4 acc2[8];
    #pragma unroll
    for (int t = 0; t < 8; ++t) acc2[t] = (f32x4){0.f, 0.f, 0.f, 0.f};
    #pragma unroll
    for (int s = 0; s < 4; ++s) {
        bf16x8 bf[8];
        #pragma unroll
        for (int t = 0; t < 8; ++t)
            bf[t] = *(const bf16x8*)&WS[((t * 4 + s) * 64 + l) * 8];
        #pragma unroll
        for (int t = 0; t < 8; ++t)
            acc2[t] = __builtin_amdgcn_mfma_f32_16x16x32_bf16(af2[s], bf[t], acc2[t], 0, 0, 0);
    }

    // ---- store Z node-major interleaved, permuted row order ----
    if (valid) {
        #pragma unroll
        for (int r = 0; r < 4; ++r) {
            int rr = 4 * g + r;
            int db = rr >> 3, dn = n8 + (rr & 7);
            unsigned zw[4];
            #pragma unroll
            for (int tt = 0; tt < 4; ++tt)
                zw[tt] = cvt_pk(acc2[2 * tt][r], acc2[2 * tt + 1][r]);
            *(uint4*)(Z + ((size_t)dn * 2 + db) * CC + c * 8) = *(uint4*)zw;
        }
    }
}

// ---------------- K2: aggregate(Z) + b2 + BN2 + GELU2 -> a2 (standard order) ----------------
// Grid-stride: wave handles nodes waveId, waveId+nw, ... Lane = (parity p, batch b, chgrp c).
// Parity p takes edge slots j+4p..j+4p+3 (two dwordx4 eg loads). GELU split across parity
// halves (4 values each); all 64 lanes do the LDS un-permute and the coalesced 8B store.
__global__ __launch_bounds__(256) void k_agg_bn(
    const u16* __restrict__ Zin, const int* __restrict__ off, const int2* __restrict__ eg,
    const float* __restrict__ b2, const float* __restrict__ g2, const float* __restrict__ be2,
    u16* __restrict__ A2, int N, int nw)
{
    __shared__ u16 TW[4][256];
    const int wv = threadIdx.x >> 6;
    const int l = threadIdx.x & 63;
    const int p = l >> 5;
    const int b = (l >> 4) & 1;
    const int c = l & 15;
    const u16* Ab = Zin + b * CC + c * 8;
    float bb[8];
    #pragma unroll
    for (int t = 0; t < 8; ++t) bb[t] = b2[t * 16 + c];

    for (int n = blockIdx.x * 4 + wv; n < N; n += nw) {
        int s = off[n], e = off[n + 1];
        float a[8] = {0.f, 0.f, 0.f, 0.f, 0.f, 0.f, 0.f, 0.f};
        for (int j = s; j < e; j += 8) {
            int base = j + 4 * p;
            uint4 ea = *(const uint4*)&eg[base];          // slots base, base+1
            uint4 eb = *(const uint4*)&eg[base + 2];      // slots base+2, base+3
            int s0 = (base     < e) ? (int)ea.x : 0; float w0 = (base     < e) ? __int_as_float((int)ea.y) : 0.f;
            int s1 = (base + 1 < e) ? (int)ea.z : 0; float w1 = (base + 1 < e) ? __int_as_float((int)ea.w) : 0.f;
            int s2 = (base + 2 < e) ? (int)eb.x : 0; float w2 = (base + 2 < e) ? __int_as_float((int)eb.y) : 0.f;
            int s3 = (base + 3 < e) ? (int)eb.z : 0; float w3 = (base + 3 < e) ? __int_as_float((int)eb.w) : 0.f;
            bf16x8 v0 = *(const bf16x8*)(Ab + (size_t)s0 * 256);
            bf16x8 v1 = *(const bf16x8*)(Ab + (size_t)s1 * 256);
            bf16x8 v2 = *(const bf16x8*)(Ab + (size_t)s2 * 256);
            bf16x8 v3 = *(const bf16x8*)(Ab + (size_t)s3 * 256);
            #pragma unroll
            for (int q = 0; q < 8; ++q) {
                a[q] = fmaf(w0, bf2f((u16)v0[q]), a[q]);
                a[q] = fmaf(w1, bf2f((u16)v1[q]), a[q]);
                a[q] = fmaf(w2, bf2f((u16)v2[q]), a[q]);
                a[q] = fmaf(w3, bf2f((u16)v3[q]), a[q]);
            }
        }
        #pragma unroll
        for (int q = 0; q < 8; ++q) a[q] += __shfl_xor(a[q], 32);   // merge parities

        // + b2, BN2 stats over 256 values (32 lanes x 8, duplicated across parity)
        float ss = 0.f, qq = 0.f;
        #pragma unroll
        for (int t = 0; t < 8; ++t) {
            float h = a[t] + bb[t];
            a[t] = h;
            ss += h;
            qq += h * h;
        }
        #pragma unroll
        for (int d = 1; d < 32; d <<= 1) {
            ss += __shfl_xor(ss, d);
            qq += __shfl_xor(qq, d);
        }
        float mean = ss * (1.f / 256.f);
        float var  = qq * (1.f / 256.f) - mean * mean;
        float sc = g2[n] * rsqrtf(fmaxf(var, 0.f) + 1e-5f);
        float sh = be2[n] - mean * sc;

        // GELU split: parity p computes q = 4p..4p+3; un-permute via LDS (all 64 lanes)
        #pragma unroll
        for (int u = 0; u < 4; ++u) {
            int q = 4 * p + u;
            TW[wv][b * CC + q * 16 + c] = f2bf(gelu_f(a[q] * sc + sh));
        }
        // wave-synchronous LDS write->read (compiler orders via lgkmcnt)
        uint2 v = *(const uint2*)&TW[wv][l * 4];
        *(uint2*)(A2 + (size_t)n * 256 + l * 4) = v;
    }
}

// ---------------- K3: aggregate(a2) -> standard-layout f32 output (coalesced) ------------
// Grid-stride. Gathers contiguous 512B/edge; stores: all 64 lanes, 16B each = 1KB/node.
__global__ __launch_bounds__(256) void k_agg_out(
    const u16* __restrict__ A2, const int* __restrict__ off, const int2* __restrict__ eg,
    float* __restrict__ Out, int N, int nw)
{
    const int l = threadIdx.x & 63;
    const int p = l >> 5;
    const int sl = l & 31;
    const u16* Ab = A2 + sl * 8;

    for (int n = blockIdx.x * 4 + (threadIdx.x >> 6); n < N; n += nw) {
        int s = off[n], e = off[n + 1];
        float a[8] = {0.f, 0.f, 0.f, 0.f, 0.f, 0.f, 0.f, 0.f};
        for (int j = s; j < e; j += 8) {
            int base = j + 4 * p;
            uint4 ea = *(const uint4*)&eg[base];
            uint4 eb = *(const uint4*)&eg[base + 2];
            int s0 = (base     < e) ? (int)ea.x : 0; float w0 = (base     < e) ? __int_as_float((int)ea.y) : 0.f;
            int s1 = (base + 1 < e) ? (int)ea.z : 0; float w1 = (base + 1 < e) ? __int_as_float((int)ea.w) : 0.f;
            int s2 = (base + 2 < e) ? (int)eb.x : 0; float w2 = (base + 2 < e) ? __int_as_float((int)eb.y) : 0.f;
            int s3 = (base + 3 < e) ? (int)eb.z : 0; float w3 = (base + 3 < e) ? __int_as_float((int)eb.w) : 0.f;
            bf16x8 v0 = *(const bf16x8*)(Ab + (size_t)s0 * 256);
            bf16x8 v1 = *(const bf16x8*)(Ab + (size_t)s1 * 256);
            bf16x8 v2 = *(const bf16x8*)(Ab + (size_t)s2 * 256);
            bf16x8 v3 = *(const bf16x8*)(Ab + (size_t)s3 * 256);
            #pragma unroll
            for (int q = 0; q < 8; ++q) {
                a[q] = fmaf(w0, bf2f((u16)v0[q]), a[q]);
                a[q] = fmaf(w1, bf2f((u16)v1[q]), a[q]);
                a[q] = fmaf(w2, bf2f((u16)v2[q]), a[q]);
                a[q] = fmaf(w3, bf2f((u16)v3[q]), a[q]);
            }
        }
        #pragma unroll
        for (int q = 0; q < 8; ++q) a[q] += __shfl_xor(a[q], 32);

        // all-64-lane store: parity0 writes a[0..3], parity1 writes a[4..7] (+16B)
        int bb_ = sl >> 4;
        int ch0 = (sl & 15) * 8;
        float* d = Out + ((size_t)bb_ * N + n) * CC + ch0 + 4 * p;
        *(float4*)d = make_float4(a[4 * p + 0], a[4 * p + 1], a[4 * p + 2], a[4 * p + 3]);
    }
}

// ---------------- launch ----------------

extern "C" void kernel_launch(void* const* d_in, const int* in_sizes, int n_in,
                              void* d_out, int out_size, void* d_ws, size_t ws_size,
                              hipStream_t stream)
{
    const float* x   = (const float*)d_in[0];
    const int*   ei  = (const int*)d_in[1];
    const float* nrm = (const float*)d_in[2];
    const float* W1  = (const float*)d_in[3];
    const float* b1  = (const float*)d_in[4];
    const float* g1  = (const float*)d_in[5];
    const float* be1 = (const float*)d_in[6];
    const float* W2  = (const float*)d_in[7];
    const float* b2  = (const float*)d_in[8];
    const float* g2  = (const float*)d_in[9];
    const float* be2 = (const float*)d_in[10];

    const int N = in_sizes[5];   // g1 has N elements
    const int E = in_sizes[2];   // norm has E elements
    const int* row = ei;         // edge_index[0] = scatter dst
    const int* col = ei + E;     // edge_index[1] = gather src
    const int nb = (N + 1023) / 1024;

    auto al = [](size_t v) { return (v + 255) & ~(size_t)255; };
    char* p = (char*)d_ws;
    int* off    = (int*)p;   p += al((size_t)(N + 1) * 4);
    int* cur    = (int*)p;   p += al((size_t)N * 4);
    int2* eg    = (int2*)p;  p += al((size_t)(E + 8) * 8);   // +8 pad: tail-slot overreads
    int* bsum   = (int*)p;   p += al((size_t)nb * 4);
    int* boff   = (int*)p;   p += al((size_t)nb * 4);
    u16* Wp1    = (u16*)p;   p += al((size_t)CC * CC * 2);
    u16* Wp2    = (u16*)p;   p += al((size_t)CC * CC * 2);
    u16* Zbuf   = (u16*)p;   p += al((size_t)2 * N * CC * 2);
    u16* A2buf  = (u16*)p;   p += al((size_t)2 * N * CC * 2);

    // CSR by destination (rebuilt every call; deterministic work)
    k_zero_i32<<<(N + 255) / 256, 256, 0, stream>>>(cur, N);
    k_hist<<<(E + 255) / 256, 256, 0, stream>>>(row, cur, E);
    k_scan_a<<<nb, 256, 0, stream>>>(cur, bsum, N);
    k_scan_b<<<1, 64, 0, stream>>>(bsum, boff, off, N, nb);
    k_scan_c<<<nb, 256, 0, stream>>>(cur, boff, off, N);   // also zeroes cur
    k_fill<<<(E + 255) / 256, 256, 0, stream>>>(row, col, nrm, off, cur, eg, E);

    // W -> bf16 fragment-order repack (W2 under the channel permutation pi)
    k_wrepack<<<(2 * CC * CC + 255) / 256, 256, 0, stream>>>(W1, Wp1, W2, Wp2);

    const int gb = (N + 31) / 32;
    const int AGG_BLOCKS = 2048;
    const int nwaves = AGG_BLOCKS * 4;
    // K1: GEMM1+BN1+GELU1+GEMM2 -> Z (node-major interleaved, permuted row order)
    k_fused_l1<<<gb, 256, 0, stream>>>(x, Wp1, Wp2, b1, g1, be1, Zbuf, N);
    // K2: aggregate + b2 + BN2 + GELU2 -> a2 (node-major, standard channel order)
    k_agg_bn<<<AGG_BLOCKS, 256, 0, stream>>>(Zbuf, off, eg, b2, g2, be2, A2buf, N, nwaves);
    // K3: aggregate -> standard f32 out (coalesced)
    k_agg_out<<<AGG_BLOCKS, 256, 0, stream>>>(A2buf, off, eg, (float*)d_out, N, nwaves);
}

// Round 12
// 153.216 us; speedup vs baseline: 1.0808x; 1.0808x over previous
//
#include <hip/hip_runtime.h>
#include <math.h>

#define CC 128      // channels (FIN=HID=OUT)

typedef unsigned short u16;
typedef short bf16x8 __attribute__((ext_vector_type(8)));
typedef float f32x4 __attribute__((ext_vector_type(4)));

typedef __attribute__((address_space(3))) void lds_t;
typedef const __attribute__((address_space(1))) void gbl_t;

__device__ __forceinline__ u16 f2bf(float f) {
    union { float f; unsigned u; } v; v.f = f;
    unsigned u = v.u;
    return (u16)((u + 0x7FFFu + ((u >> 16) & 1u)) >> 16);   // RNE
}
__device__ __forceinline__ float bf2f(unsigned hi16) {
    union { unsigned u; float f; } v; v.u = hi16 << 16; return v.f;
}
// HW packed f32->bf16 (RNE): 2 values in 1 instruction.
__device__ __forceinline__ unsigned cvt_pk(float lo, float hi) {
    unsigned r;
    asm("v_cvt_pk_bf16_f32 %0, %1, %2" : "=v"(r) : "v"(lo), "v"(hi));
    return r;
}

// Exact-GELU via branch-free A&S 7.1.26 erf (|err| < 1.5e-7).
__device__ __forceinline__ float gelu_f(float y) {
    float xa = fabsf(y) * 0.70710678118654752f;
    float t  = __builtin_amdgcn_rcpf(fmaf(0.3275911f, xa, 1.0f));
    float p  = fmaf(1.061405429f, t, -1.453152027f);
    p = fmaf(p, t, 1.421413741f);
    p = fmaf(p, t, -0.284496736f);
    p = fmaf(p, t, 0.254829592f);
    p *= t;
    float e  = __expf(-xa * xa);
    float er = fmaf(-p, e, 1.0f);
    float s  = copysignf(er, y);
    return 0.5f * y * (1.0f + s);
}

// ---------------- CSR build ----------------

__global__ __launch_bounds__(256) void k_zero_i32(int* __restrict__ p, int n) {
    int i = blockIdx.x * 256 + threadIdx.x;
    if (i < n) p[i] = 0;
}

__global__ __launch_bounds__(256) void k_hist(const int* __restrict__ row, int* __restrict__ cnt, int E) {
    int e = blockIdx.x * 256 + threadIdx.x;
    if (e < E) atomicAdd(&cnt[row[e]], 1);
}

__device__ __forceinline__ int wave_incl_scan(int v) {
    #pragma unroll
    for (int d = 1; d < 64; d <<= 1) {
        int t = __shfl_up(v, d);
        if ((threadIdx.x & 63) >= d) v += t;
    }
    return v;
}

__global__ __launch_bounds__(256) void k_scan_a(const int* __restrict__ cnt, int* __restrict__ bsum, int N) {
    int base = blockIdx.x * 1024 + threadIdx.x * 4;
    int s = 0;
    #pragma unroll
    for (int u = 0; u < 4; ++u) { int i = base + u; if (i < N) s += cnt[i]; }
    #pragma unroll
    for (int d = 32; d > 0; d >>= 1) s += __shfl_down(s, d);
    __shared__ int wsum[4];
    if ((threadIdx.x & 63) == 0) wsum[threadIdx.x >> 6] = s;
    __syncthreads();
    if (threadIdx.x == 0) bsum[blockIdx.x] = wsum[0] + wsum[1] + wsum[2] + wsum[3];
}

__global__ __launch_bounds__(64) void k_scan_b(const int* __restrict__ bsum, int* __restrict__ boff,
                                               int* __restrict__ off, int N, int nb) {
    int carry = 0;
    for (int base = 0; base < nb; base += 64) {
        int t = base + (int)threadIdx.x;
        int v = (t < nb) ? bsum[t] : 0;
        int incl = wave_incl_scan(v);
        if (t < nb) boff[t] = carry + incl - v;
        carry += __shfl(incl, 63);
    }
    if (threadIdx.x == 0) off[N] = carry;
}

__global__ __launch_bounds__(256) void k_scan_c(int* __restrict__ cnt, const int* __restrict__ boff,
                                                int* __restrict__ off, int N) {
    int t = threadIdx.x;
    int base = blockIdx.x * 1024 + t * 4;
    int v[4]; int s = 0;
    #pragma unroll
    for (int u = 0; u < 4; ++u) { int i = base + u; v[u] = (i < N) ? cnt[i] : 0; s += v[u]; }
    int incl = wave_incl_scan(s);
    __shared__ int wsum[4];
    int w = t >> 6, lane = t & 63;
    if (lane == 63) wsum[w] = incl;
    __syncthreads();
    int run = incl - s + boff[blockIdx.x];
    for (int ww = 0; ww < w; ++ww) run += wsum[ww];
    #pragma unroll
    for (int u = 0; u < 4; ++u) {
        int i = base + u;
        if (i < N) { off[i] = run; cnt[i] = 0; }
        run += v[u];
    }
}

__global__ __launch_bounds__(256) void k_fill(const int* __restrict__ row, const int* __restrict__ col,
                                              const float* __restrict__ nrm, const int* __restrict__ off,
                                              int* __restrict__ cur, int2* __restrict__ eg, int E) {
    int e = blockIdx.x * 256 + threadIdx.x;
    if (e < E) {
        int r = row[e];
        int p = off[r] + atomicAdd(&cur[r], 1);
        eg[p] = make_int2(col[e], __float_as_int(nrm[e]));
    }
}

// ---------------- W repack into MFMA B-fragment order ----------------
// W1: standard k-order. W2: k-order permuted by pi(p) = (p&7)*16 + (p>>3), matching the
// channel-permuted layout the fused kernel stores Z in (position p holds channel pi(p)).
__global__ __launch_bounds__(256) void k_wrepack(const float* __restrict__ W1, u16* __restrict__ Wp1,
                                                 const float* __restrict__ W2, u16* __restrict__ Wp2) {
    int i = blockIdx.x * 256 + threadIdx.x;
    if (i < 2 * CC * CC) {
        int is2 = (i >= CC * CC);
        int ii = is2 ? i - CC * CC : i;
        int j = ii & 7, l = (ii >> 3) & 63, s = (ii >> 9) & 3, t = ii >> 11;
        int r = 16 * t + (l & 15);
        int p = s * 32 + ((l >> 4) & 3) * 8 + j;             // fragment k-position 0..127
        if (is2) {
            int k = (p & 7) * 16 + (p >> 3);                 // pi(p)
            Wp2[ii] = f2bf(W2[r * CC + k]);
        } else {
            Wp1[ii] = f2bf(W1[r * CC + p]);
        }
    }
}

// ---------------- K1: GEMM1 + BN1 + GELU1 + GEMM2 (fused) ----------------
// Z stored NODE-MAJOR interleaved: Z[node][batch][128] (permuted channel order within row).
__global__ __launch_bounds__(256) void k_fused_l1(
    const float* __restrict__ X, const u16* __restrict__ Wp1, const u16* __restrict__ Wp2,
    const float* __restrict__ bias, const float* __restrict__ gamma, const float* __restrict__ beta,
    u16* __restrict__ Z, int N)
{
    __shared__ __align__(16) u16 WS[CC * CC];          // 32KB: W1 in pass1, W2 in pass2
    __shared__ __align__(16) unsigned TT[4][16][68];   // per-wave A1 transpose

    const int tid = threadIdx.x;
    const int w = tid >> 6;
    const int l = tid & 63;
    const int g = l >> 4;
    const int c = l & 15;
    const int n8 = blockIdx.x * 32 + w * 8;
    const bool valid = n8 < N;
    const int nbase = valid ? n8 : 0;

    // ---- stage W1 -> LDS (async DMA, 32KB/block) ----
    #pragma unroll
    for (int it = 0; it < 8; ++it) {
        const u16* gsrc = Wp1 + it * 2048 + w * 512 + l * 8;
        u16* ldst = &WS[it * 2048 + w * 512];
        __builtin_amdgcn_global_load_lds((gbl_t*)gsrc, (lds_t*)ldst, 16, 0, 0);
    }

    // ---- A fragments from X (f32), rides under the DMA ----
    const int ab = c >> 3;
    const int an = nbase + (c & 7);
    const float* xbase = X + ((size_t)ab * N + an) * CC + g * 8;
    bf16x8 af[4];
    #pragma unroll
    for (int s = 0; s < 4; ++s) {
        float4 lo = *(const float4*)(xbase + s * 32);
        float4 hi = *(const float4*)(xbase + s * 32 + 4);
        unsigned aw[4];
        aw[0] = cvt_pk(lo.x, lo.y); aw[1] = cvt_pk(lo.z, lo.w);
        aw[2] = cvt_pk(hi.x, hi.y); aw[3] = cvt_pk(hi.z, hi.w);
        af[s] = *(bf16x8*)aw;
    }

    // epilogue params
    float bb[8];
    #pragma unroll
    for (int t = 0; t < 8; ++t) bb[t] = bias[t * 16 + c];
    float gam[4], bet[4];
    #pragma unroll
    for (int r = 0; r < 4; ++r) {
        int p = (4 * g + r) & 7;
        gam[r] = gamma[nbase + p];
        bet[r] = beta[nbase + p];
    }

    __syncthreads();   // W1 staged

    // ---- MFMA pass 1 ----
    f32x4 acc[8];
    #pragma unroll
    for (int t = 0; t < 8; ++t) acc[t] = (f32x4){0.f, 0.f, 0.f, 0.f};
    #pragma unroll
    for (int s = 0; s < 4; ++s) {
        bf16x8 bf[8];
        #pragma unroll
        for (int t = 0; t < 8; ++t)
            bf[t] = *(const bf16x8*)&WS[((t * 4 + s) * 64 + l) * 8];
        #pragma unroll
        for (int t = 0; t < 8; ++t)
            acc[t] = __builtin_amdgcn_mfma_f32_16x16x32_bf16(af[s], bf[t], acc[t], 0, 0, 0);
    }

    __syncthreads();   // all waves done reading W1

    // ---- stage W2 into same LDS; latency hidden under the epilogue ----
    #pragma unroll
    for (int it = 0; it < 8; ++it) {
        const u16* gsrc = Wp2 + it * 2048 + w * 512 + l * 8;
        u16* ldst = &WS[it * 2048 + w * 512];
        __builtin_amdgcn_global_load_lds((gbl_t*)gsrc, (lds_t*)ldst, 16, 0, 0);
    }

    // ---- bias + BN1 stats ----
    float rs[4] = {0.f, 0.f, 0.f, 0.f}, rq[4] = {0.f, 0.f, 0.f, 0.f};
    #pragma unroll
    for (int t = 0; t < 8; ++t)
        #pragma unroll
        for (int r = 0; r < 4; ++r) {
            float h = acc[t][r] + bb[t];
            acc[t][r] = h;
            rs[r] += h;
            rq[r] += h * h;
        }
    #pragma unroll
    for (int d = 1; d < 16; d <<= 1) {
        #pragma unroll
        for (int r = 0; r < 4; ++r) {
            rs[r] += __shfl_xor(rs[r], d);
            rq[r] += __shfl_xor(rq[r], d);
        }
    }
    #pragma unroll
    for (int r = 0; r < 4; ++r) {
        rs[r] += __shfl_xor(rs[r], 32);
        rq[r] += __shfl_xor(rq[r], 32);
    }

    // ---- BN1 + GELU1 ----
    #pragma unroll
    for (int r = 0; r < 4; ++r) {
        float mean = rs[r] * (1.f / 256.f);
        float var  = rq[r] * (1.f / 256.f) - mean * mean;
        float sc = gam[r] * rsqrtf(fmaxf(var, 0.f) + 1e-5f);
        float sh = bet[r] - mean * sc;
        #pragma unroll
        for (int t = 0; t < 8; ++t)
            acc[t][r] = gelu_f(acc[t][r] * sc + sh);
    }

    // ---- A1 -> wave-private LDS tile (permuted pos c*8+t), then A2-fragments ----
    #pragma unroll
    for (int r = 0; r < 4; ++r) {
        unsigned tw[4];
        #pragma unroll
        for (int tt = 0; tt < 4; ++tt)
            tw[tt] = cvt_pk(acc[2 * tt][r], acc[2 * tt + 1][r]);
        *(uint4*)&TT[w][4 * g + r][c * 4] = *(uint4*)tw;
    }
    bf16x8 af2[4];
    #pragma unroll
    for (int s = 0; s < 4; ++s)
        af2[s] = *(const bf16x8*)&TT[w][c][s * 16 + g * 4];

    __syncthreads();   // W2 staged

    // ---- MFMA pass 2 ----
    f32x4 acc2[8];
    #pragma unroll
    for (int t = 0; t < 8; ++t) acc2[t] = (f32x4){0.f, 0.f, 0.f, 0.f};
    #pragma unroll
    for (int s = 0; s < 4; ++s) {
        bf16x8 bf[8];
        #pragma unroll
        for (int t = 0; t < 8; ++t)
            bf[t] = *(const bf16x8*)&WS[((t * 4 + s) * 64 + l) * 8];
        #pragma unroll
        for (int t = 0; t < 8; ++t)
            acc2[t] = __builtin_amdgcn_mfma_f32_16x16x32_bf16(af2[s], bf[t], acc2[t], 0, 0, 0);
    }

    // ---- store Z node-major interleaved, permuted row order ----
    if (valid) {
        #pragma unroll
        for (int r = 0; r < 4; ++r) {
            int rr = 4 * g + r;
            int db = rr >> 3, dn = n8 + (rr & 7);
            unsigned zw[4];
            #pragma unroll
            for (int tt = 0; tt < 4; ++tt)
                zw[tt] = cvt_pk(acc2[2 * tt][r], acc2[2 * tt + 1][r]);
            *(uint4*)(Z + ((size_t)dn * 2 + db) * CC + c * 8) = *(uint4*)zw;
        }
    }
}

// ---------------- K2: aggregate(Z) + b2 + BN2 + GELU2 -> a2 (standard order) ----------------
// TWO nodes per wave (one per 32-lane half) -- no duplicated epilogue work.
// Half-lane h: batch b = h>>4, chgrp c = h&15. Edge loop 4-deep unrolled per half.
// BN2 stats reduce with shfl_xor(1..16) which stays inside each half.
__global__ __launch_bounds__(256) void k_agg_bn(
    const u16* __restrict__ Zin, const int* __restrict__ off, const int2* __restrict__ eg,
    const float* __restrict__ b2, const float* __restrict__ g2, const float* __restrict__ be2,
    u16* __restrict__ A2, int N)
{
    __shared__ u16 TW[4][2][256];
    const int wv = threadIdx.x >> 6;
    const int l = threadIdx.x & 63;
    const int half = l >> 5;
    const int h = l & 31;
    const int b = h >> 4;
    const int c = h & 15;
    const int n = blockIdx.x * 8 + wv * 2 + half;
    const bool nv = n < N;
    const int nn = nv ? n : 0;
    const u16* Ab = Zin + b * CC + c * 8;

    float bb[8];
    #pragma unroll
    for (int t = 0; t < 8; ++t) bb[t] = b2[t * 16 + c];

    int s = off[nn];
    int e = nv ? off[nn + 1] : 0;
    float a[8] = {0.f, 0.f, 0.f, 0.f, 0.f, 0.f, 0.f, 0.f};
    for (int j = s; j < e; j += 4) {
        int2 e0 = eg[j], e1 = eg[j + 1], e2 = eg[j + 2], e3 = eg[j + 3];
        int s0 = e0.x;                  float w0 = __int_as_float(e0.y);
        int s1 = (j + 1 < e) ? e1.x : 0; float w1 = (j + 1 < e) ? __int_as_float(e1.y) : 0.f;
        int s2 = (j + 2 < e) ? e2.x : 0; float w2 = (j + 2 < e) ? __int_as_float(e2.y) : 0.f;
        int s3 = (j + 3 < e) ? e3.x : 0; float w3 = (j + 3 < e) ? __int_as_float(e3.y) : 0.f;
        bf16x8 v0 = *(const bf16x8*)(Ab + (size_t)s0 * 256);
        bf16x8 v1 = *(const bf16x8*)(Ab + (size_t)s1 * 256);
        bf16x8 v2 = *(const bf16x8*)(Ab + (size_t)s2 * 256);
        bf16x8 v3 = *(const bf16x8*)(Ab + (size_t)s3 * 256);
        #pragma unroll
        for (int q = 0; q < 8; ++q) {
            a[q] = fmaf(w0, bf2f((u16)v0[q]), a[q]);
            a[q] = fmaf(w1, bf2f((u16)v1[q]), a[q]);
            a[q] = fmaf(w2, bf2f((u16)v2[q]), a[q]);
            a[q] = fmaf(w3, bf2f((u16)v3[q]), a[q]);
        }
    }

    // + b2, BN2 stats over this half's 32 lanes x 8 values = 256
    float ss = 0.f, qq = 0.f;
    #pragma unroll
    for (int t = 0; t < 8; ++t) {
        float hh = a[t] + bb[t];
        a[t] = hh;
        ss += hh;
        qq += hh * hh;
    }
    #pragma unroll
    for (int d = 1; d < 32; d <<= 1) {   // masks 1..16: stays within the 32-lane half
        ss += __shfl_xor(ss, d);
        qq += __shfl_xor(qq, d);
    }
    float mean = ss * (1.f / 256.f);
    float var  = qq * (1.f / 256.f) - mean * mean;
    float sc = g2[nn] * rsqrtf(fmaxf(var, 0.f) + 1e-5f);
    float sh = be2[nn] - mean * sc;

    // GELU + un-permute via LDS (channel t*16+c <- permuted slot), coalesced store
    #pragma unroll
    for (int t = 0; t < 8; ++t)
        TW[wv][half][b * CC + t * 16 + c] = f2bf(gelu_f(a[t] * sc + sh));
    // wave-synchronous LDS write->read (compiler orders via lgkmcnt)
    if (nv) {
        bf16x8 v = *(const bf16x8*)&TW[wv][half][h * 8];
        *(bf16x8*)(A2 + (size_t)nn * 256 + h * 8) = v;
    }
}

// ---------------- K3: aggregate(a2) -> standard-layout f32 output ----------------
// TWO nodes per wave; gathers contiguous 512B/edge; stores 32B/lane coalesced.
__global__ __launch_bounds__(256) void k_agg_out(
    const u16* __restrict__ A2, const int* __restrict__ off, const int2* __restrict__ eg,
    float* __restrict__ Out, int N)
{
    const int wv = threadIdx.x >> 6;
    const int l = threadIdx.x & 63;
    const int half = l >> 5;
    const int h = l & 31;
    const int b = h >> 4;
    const int c = h & 15;
    const int n = blockIdx.x * 8 + wv * 2 + half;
    const bool nv = n < N;
    const int nn = nv ? n : 0;
    const u16* Ab = A2 + h * 8;   // standard order: h covers 256 values of a node row

    int s = off[nn];
    int e = nv ? off[nn + 1] : 0;
    float a[8] = {0.f, 0.f, 0.f, 0.f, 0.f, 0.f, 0.f, 0.f};
    for (int j = s; j < e; j += 4) {
        int2 e0 = eg[j], e1 = eg[j + 1], e2 = eg[j + 2], e3 = eg[j + 3];
        int s0 = e0.x;                  float w0 = __int_as_float(e0.y);
        int s1 = (j + 1 < e) ? e1.x : 0; float w1 = (j + 1 < e) ? __int_as_float(e1.y) : 0.f;
        int s2 = (j + 2 < e) ? e2.x : 0; float w2 = (j + 2 < e) ? __int_as_float(e2.y) : 0.f;
        int s3 = (j + 3 < e) ? e3.x : 0; float w3 = (j + 3 < e) ? __int_as_float(e3.y) : 0.f;
        bf16x8 v0 = *(const bf16x8*)(Ab + (size_t)s0 * 256);
        bf16x8 v1 = *(const bf16x8*)(Ab + (size_t)s1 * 256);
        bf16x8 v2 = *(const bf16x8*)(Ab + (size_t)s2 * 256);
        bf16x8 v3 = *(const bf16x8*)(Ab + (size_t)s3 * 256);
        #pragma unroll
        for (int q = 0; q < 8; ++q) {
            a[q] = fmaf(w0, bf2f((u16)v0[q]), a[q]);
            a[q] = fmaf(w1, bf2f((u16)v1[q]), a[q]);
            a[q] = fmaf(w2, bf2f((u16)v2[q]), a[q]);
            a[q] = fmaf(w3, bf2f((u16)v3[q]), a[q]);
        }
    }
    if (nv) {
        // lane h holds channels h*8..h*8+7 of node row [b][c*8..]; b = h>>4, ch0 = (h&15)*8
        float* d = Out + ((size_t)b * N + nn) * CC + c * 8;
        *(float4*)&d[0] = make_float4(a[0], a[1], a[2], a[3]);
        *(float4*)&d[4] = make_float4(a[4], a[5], a[6], a[7]);
    }
}

// ---------------- launch ----------------

extern "C" void kernel_launch(void* const* d_in, const int* in_sizes, int n_in,
                              void* d_out, int out_size, void* d_ws, size_t ws_size,
                              hipStream_t stream)
{
    const float* x   = (const float*)d_in[0];
    const int*   ei  = (const int*)d_in[1];
    const float* nrm = (const float*)d_in[2];
    const float* W1  = (const float*)d_in[3];
    const float* b1  = (const float*)d_in[4];
    const float* g1  = (const float*)d_in[5];
    const float* be1 = (const float*)d_in[6];
    const float* W2  = (const float*)d_in[7];
    const float* b2  = (const float*)d_in[8];
    const float* g2  = (const float*)d_in[9];
    const float* be2 = (const float*)d_in[10];

    const int N = in_sizes[5];   // g1 has N elements
    const int E = in_sizes[2];   // norm has E elements
    const int* row = ei;         // edge_index[0] = scatter dst
    const int* col = ei + E;     // edge_index[1] = gather src
    const int nb = (N + 1023) / 1024;

    auto al = [](size_t v) { return (v + 255) & ~(size_t)255; };
    char* p = (char*)d_ws;
    int* off    = (int*)p;   p += al((size_t)(N + 1) * 4);
    int* cur    = (int*)p;   p += al((size_t)N * 4);
    int2* eg    = (int2*)p;  p += al((size_t)(E + 8) * 8);   // +8 pad: tail-slot overreads
    int* bsum   = (int*)p;   p += al((size_t)nb * 4);
    int* boff   = (int*)p;   p += al((size_t)nb * 4);
    u16* Wp1    = (u16*)p;   p += al((size_t)CC * CC * 2);
    u16* Wp2    = (u16*)p;   p += al((size_t)CC * CC * 2);
    u16* Zbuf   = (u16*)p;   p += al((size_t)2 * N * CC * 2);
    u16* A2buf  = (u16*)p;   p += al((size_t)2 * N * CC * 2);

    // CSR by destination (rebuilt every call; deterministic work)
    k_zero_i32<<<(N + 255) / 256, 256, 0, stream>>>(cur, N);
    k_hist<<<(E + 255) / 256, 256, 0, stream>>>(row, cur, E);
    k_scan_a<<<nb, 256, 0, stream>>>(cur, bsum, N);
    k_scan_b<<<1, 64, 0, stream>>>(bsum, boff, off, N, nb);
    k_scan_c<<<nb, 256, 0, stream>>>(cur, boff, off, N);   // also zeroes cur
    k_fill<<<(E + 255) / 256, 256, 0, stream>>>(row, col, nrm, off, cur, eg, E);

    // W -> bf16 fragment-order repack (W2 under the channel permutation pi)
    k_wrepack<<<(2 * CC * CC + 255) / 256, 256, 0, stream>>>(W1, Wp1, W2, Wp2);

    const int gb = (N + 31) / 32;
    const int ga = (N + 7) / 8;
    // K1: GEMM1+BN1+GELU1+GEMM2 -> Z (node-major interleaved, permuted row order)
    k_fused_l1<<<gb, 256, 0, stream>>>(x, Wp1, Wp2, b1, g1, be1, Zbuf, N);
    // K2: aggregate + b2 + BN2 + GELU2 -> a2 (node-major, standard channel order)
    k_agg_bn<<<ga, 256, 0, stream>>>(Zbuf, off, eg, b2, g2, be2, A2buf, N);
    // K3: aggregate -> standard f32 out (coalesced)
    k_agg_out<<<ga, 256, 0, stream>>>(A2buf, off, eg, (float*)d_out, N);
}

// Round 13
// 150.167 us; speedup vs baseline: 1.1027x; 1.0203x over previous
//
#include <hip/hip_runtime.h>
#include <math.h>

#define CC 128      // channels (FIN=HID=OUT)

typedef unsigned short u16;
typedef short bf16x8 __attribute__((ext_vector_type(8)));
typedef float f32x4 __attribute__((ext_vector_type(4)));

typedef __attribute__((address_space(3))) void lds_t;
typedef const __attribute__((address_space(1))) void gbl_t;

__device__ __forceinline__ u16 f2bf(float f) {
    union { float f; unsigned u; } v; v.f = f;
    unsigned u = v.u;
    return (u16)((u + 0x7FFFu + ((u >> 16) & 1u)) >> 16);   // RNE
}
__device__ __forceinline__ float bf2f(unsigned hi16) {
    union { unsigned u; float f; } v; v.u = hi16 << 16; return v.f;
}
// HW packed f32->bf16 (RNE): 2 values in 1 instruction.
__device__ __forceinline__ unsigned cvt_pk(float lo, float hi) {
    unsigned r;
    asm("v_cvt_pk_bf16_f32 %0, %1, %2" : "=v"(r) : "v"(lo), "v"(hi));
    return r;
}

// Exact-GELU via branch-free A&S 7.1.26 erf (|err| < 1.5e-7).
__device__ __forceinline__ float gelu_f(float y) {
    float xa = fabsf(y) * 0.70710678118654752f;
    float t  = __builtin_amdgcn_rcpf(fmaf(0.3275911f, xa, 1.0f));
    float p  = fmaf(1.061405429f, t, -1.453152027f);
    p = fmaf(p, t, 1.421413741f);
    p = fmaf(p, t, -0.284496736f);
    p = fmaf(p, t, 0.254829592f);
    p *= t;
    float e  = __expf(-xa * xa);
    float er = fmaf(-p, e, 1.0f);
    float s  = copysignf(er, y);
    return 0.5f * y * (1.0f + s);
}

// ---------------- CSR build ----------------

__global__ __launch_bounds__(256) void k_hist(const int* __restrict__ row, int* __restrict__ cnt, int E) {
    int e = blockIdx.x * 256 + threadIdx.x;
    if (e < E) atomicAdd(&cnt[row[e]], 1);
}

__device__ __forceinline__ int wave_incl_scan(int v) {
    #pragma unroll
    for (int d = 1; d < 64; d <<= 1) {
        int t = __shfl_up(v, d);
        if ((threadIdx.x & 63) >= d) v += t;
    }
    return v;
}

__global__ __launch_bounds__(256) void k_scan_a(const int* __restrict__ cnt, int* __restrict__ bsum, int N) {
    int base = blockIdx.x * 1024 + threadIdx.x * 4;
    int s = 0;
    #pragma unroll
    for (int u = 0; u < 4; ++u) { int i = base + u; if (i < N) s += cnt[i]; }
    #pragma unroll
    for (int d = 32; d > 0; d >>= 1) s += __shfl_down(s, d);
    __shared__ int wsum[4];
    if ((threadIdx.x & 63) == 0) wsum[threadIdx.x >> 6] = s;
    __syncthreads();
    if (threadIdx.x == 0) bsum[blockIdx.x] = wsum[0] + wsum[1] + wsum[2] + wsum[3];
}

__global__ __launch_bounds__(64) void k_scan_b(const int* __restrict__ bsum, int* __restrict__ boff,
                                               int* __restrict__ off, int N, int nb) {
    int carry = 0;
    for (int base = 0; base < nb; base += 64) {
        int t = base + (int)threadIdx.x;
        int v = (t < nb) ? bsum[t] : 0;
        int incl = wave_incl_scan(v);
        if (t < nb) boff[t] = carry + incl - v;
        carry += __shfl(incl, 63);
    }
    if (threadIdx.x == 0) off[N] = carry;
}

__global__ __launch_bounds__(256) void k_scan_c(int* __restrict__ cnt, const int* __restrict__ boff,
                                                int* __restrict__ off, int N) {
    int t = threadIdx.x;
    int base = blockIdx.x * 1024 + t * 4;
    int v[4]; int s = 0;
    #pragma unroll
    for (int u = 0; u < 4; ++u) { int i = base + u; v[u] = (i < N) ? cnt[i] : 0; s += v[u]; }
    int incl = wave_incl_scan(s);
    __shared__ int wsum[4];
    int w = t >> 6, lane = t & 63;
    if (lane == 63) wsum[w] = incl;
    __syncthreads();
    int run = incl - s + boff[blockIdx.x];
    for (int ww = 0; ww < w; ++ww) run += wsum[ww];
    #pragma unroll
    for (int u = 0; u < 4; ++u) {
        int i = base + u;
        if (i < N) { off[i] = run; cnt[i] = 0; }
        run += v[u];
    }
}

__global__ __launch_bounds__(256) void k_fill(const int* __restrict__ row, const int* __restrict__ col,
                                              const float* __restrict__ nrm, const int* __restrict__ off,
                                              int* __restrict__ cur, int2* __restrict__ eg, int E) {
    int e = blockIdx.x * 256 + threadIdx.x;
    if (e < E) {
        int r = row[e];
        int p = off[r] + atomicAdd(&cur[r], 1);
        eg[p] = make_int2(col[e], __float_as_int(nrm[e]));
    }
}

// ---------------- prep: zero cur  +  W repack into MFMA B-fragment order ----------------
// W1: standard k-order. W2: k-order permuted by pi(p) = (p&7)*16 + (p>>3), matching the
// channel-permuted layout the fused kernel stores Z in (position p holds channel pi(p)).
__global__ __launch_bounds__(256) void k_prep(int* __restrict__ cur, int N,
                                              const float* __restrict__ W1, u16* __restrict__ Wp1,
                                              const float* __restrict__ W2, u16* __restrict__ Wp2) {
    int i = blockIdx.x * 256 + threadIdx.x;
    if (i < N) { cur[i] = 0; return; }
    int iw = i - N;
    if (iw < 2 * CC * CC) {
        int is2 = (iw >= CC * CC);
        int ii = is2 ? iw - CC * CC : iw;
        int j = ii & 7, l = (ii >> 3) & 63, s = (ii >> 9) & 3, t = ii >> 11;
        int r = 16 * t + (l & 15);
        int p = s * 32 + ((l >> 4) & 3) * 8 + j;             // fragment k-position 0..127
        if (is2) {
            int k = (p & 7) * 16 + (p >> 3);                 // pi(p)
            Wp2[ii] = f2bf(W2[r * CC + k]);
        } else {
            Wp1[ii] = f2bf(W1[r * CC + p]);
        }
    }
}

// ---------------- K1: persistent fused GEMM1+BN1+GELU1+GEMM2, barrier-free loop ----------
// W1 AND W2 staged once per block (64KB); TT transpose = 16KB XOR-swizzled (stride-64 u32,
// col ^= (row&7)<<2 -> 2-way-free banks on write and read). LDS = exactly 80KB -> 2
// blocks/CU. Each block loops over tiles (32 nodes each) with ZERO in-loop barriers:
// W is read-only, TT is wave-private. Next tile's X/gamma/beta prefetched mid-loop.
__global__ __launch_bounds__(256, 2) void k_fused_l1(
    const float* __restrict__ X, const u16* __restrict__ Wp1, const u16* __restrict__ Wp2,
    const float* __restrict__ bias, const float* __restrict__ gamma, const float* __restrict__ beta,
    u16* __restrict__ Z, int N)
{
    __shared__ __align__(16) u16 WS1[CC * CC];        // 32KB, W1 resident
    __shared__ __align__(16) u16 WS2[CC * CC];        // 32KB, W2 resident
    __shared__ __align__(16) unsigned TT[4][16][64];  // 16KB, XOR-swizzled transpose

    const int tid = threadIdx.x;
    const int w = tid >> 6;
    const int l = tid & 63;
    const int g = l >> 4;
    const int c = l & 15;
    const int ntiles = (N + 31) / 32;
    const int NB = gridDim.x;

    // ---- stage W1 + W2 once (async DMA, 64KB/block) ----
    #pragma unroll
    for (int it = 0; it < 8; ++it) {
        const u16* g1s = Wp1 + it * 2048 + w * 512 + l * 8;
        const u16* g2s = Wp2 + it * 2048 + w * 512 + l * 8;
        __builtin_amdgcn_global_load_lds((gbl_t*)g1s, (lds_t*)&WS1[it * 2048 + w * 512], 16, 0, 0);
        __builtin_amdgcn_global_load_lds((gbl_t*)g2s, (lds_t*)&WS2[it * 2048 + w * 512], 16, 0, 0);
    }

    // bias is tile-independent
    float bb[8];
    #pragma unroll
    for (int t = 0; t < 8; ++t) bb[t] = bias[t * 16 + c];

    // ---- X / gamma / beta prefetch registers ----
    float4 xlo[4], xhi[4];
    float gamv[4], betv[4];
    auto prefetch = [&](int tt) {
        int n8 = tt * 32 + w * 8;
        int nb_ = (n8 < N) ? n8 : 0;
        const float* xb = X + ((size_t)(c >> 3) * N + nb_ + (c & 7)) * CC + g * 8;
        #pragma unroll
        for (int s = 0; s < 4; ++s) {
            xlo[s] = *(const float4*)(xb + s * 32);
            xhi[s] = *(const float4*)(xb + s * 32 + 4);
        }
        #pragma unroll
        for (int r = 0; r < 4; ++r) {
            int p = (4 * g + r) & 7;
            gamv[r] = gamma[nb_ + p];
            betv[r] = beta[nb_ + p];
        }
    };
    prefetch(blockIdx.x);

    __syncthreads();   // W1+W2 staged (barrier drains vmcnt); the ONLY barrier

    for (int t = blockIdx.x; t < ntiles; t += NB) {
        const int n8 = t * 32 + w * 8;
        const bool valid = n8 < N;

        // consume prefetched X -> A fragments; copy gamma/beta
        bf16x8 af[4];
        #pragma unroll
        for (int s = 0; s < 4; ++s) {
            unsigned aw[4];
            aw[0] = cvt_pk(xlo[s].x, xlo[s].y); aw[1] = cvt_pk(xlo[s].z, xlo[s].w);
            aw[2] = cvt_pk(xhi[s].x, xhi[s].y); aw[3] = cvt_pk(xhi[s].z, xhi[s].w);
            af[s] = *(bf16x8*)aw;
        }
        float gam[4], bet[4];
        #pragma unroll
        for (int r = 0; r < 4; ++r) { gam[r] = gamv[r]; bet[r] = betv[r]; }

        // issue next tile's prefetch (hides under this tile's compute)
        if (t + NB < ntiles) prefetch(t + NB);

        // ---- MFMA pass 1: h1 = X * W1^T ----
        f32x4 acc[8];
        #pragma unroll
        for (int q = 0; q < 8; ++q) acc[q] = (f32x4){0.f, 0.f, 0.f, 0.f};
        #pragma unroll
        for (int s = 0; s < 4; ++s) {
            bf16x8 bf[8];
            #pragma unroll
            for (int q = 0; q < 8; ++q)
                bf[q] = *(const bf16x8*)&WS1[((q * 4 + s) * 64 + l) * 8];
            #pragma unroll
            for (int q = 0; q < 8; ++q)
                acc[q] = __builtin_amdgcn_mfma_f32_16x16x32_bf16(af[s], bf[q], acc[q], 0, 0, 0);
        }

        // ---- bias + BN1 stats (wave-local) ----
        float rs[4] = {0.f, 0.f, 0.f, 0.f}, rq[4] = {0.f, 0.f, 0.f, 0.f};
        #pragma unroll
        for (int q = 0; q < 8; ++q)
            #pragma unroll
            for (int r = 0; r < 4; ++r) {
                float h = acc[q][r] + bb[q];
                acc[q][r] = h;
                rs[r] += h;
                rq[r] += h * h;
            }
        #pragma unroll
        for (int d = 1; d < 16; d <<= 1) {
            #pragma unroll
            for (int r = 0; r < 4; ++r) {
                rs[r] += __shfl_xor(rs[r], d);
                rq[r] += __shfl_xor(rq[r], d);
            }
        }
        #pragma unroll
        for (int r = 0; r < 4; ++r) {
            rs[r] += __shfl_xor(rs[r], 32);
            rq[r] += __shfl_xor(rq[r], 32);
        }

        // ---- BN1 + GELU1 in registers ----
        #pragma unroll
        for (int r = 0; r < 4; ++r) {
            float mean = rs[r] * (1.f / 256.f);
            float var  = rq[r] * (1.f / 256.f) - mean * mean;
            float sc = gam[r] * rsqrtf(fmaxf(var, 0.f) + 1e-5f);
            float sh = bet[r] - mean * sc;
            #pragma unroll
            for (int q = 0; q < 8; ++q)
                acc[q][r] = gelu_f(acc[q][r] * sc + sh);
        }

        // ---- A1 -> wave-private XOR-swizzled LDS transpose, then A2-fragments ----
        #pragma unroll
        for (int r = 0; r < 4; ++r) {
            int row = 4 * g + r;
            unsigned tw[4];
            #pragma unroll
            for (int tt = 0; tt < 4; ++tt)
                tw[tt] = cvt_pk(acc[2 * tt][r], acc[2 * tt + 1][r]);
            int colw = (c * 4) ^ ((row & 7) << 2);
            *(uint4*)&TT[w][row][colw] = *(uint4*)tw;
        }
        bf16x8 af2[4];
        #pragma unroll
        for (int s = 0; s < 4; ++s) {
            int colr = (s * 16 + g * 4) ^ ((c & 7) << 2);
            af2[s] = *(const bf16x8*)&TT[w][c][colr];   // same-wave, lgkmcnt-ordered
        }

        // ---- MFMA pass 2: Z = A1 * W2^T ----
        f32x4 acc2[8];
        #pragma unroll
        for (int q = 0; q < 8; ++q) acc2[q] = (f32x4){0.f, 0.f, 0.f, 0.f};
        #pragma unroll
        for (int s = 0; s < 4; ++s) {
            bf16x8 bf[8];
            #pragma unroll
            for (int q = 0; q < 8; ++q)
                bf[q] = *(const bf16x8*)&WS2[((q * 4 + s) * 64 + l) * 8];
            #pragma unroll
            for (int q = 0; q < 8; ++q)
                acc2[q] = __builtin_amdgcn_mfma_f32_16x16x32_bf16(af2[s], bf[q], acc2[q], 0, 0, 0);
        }

        // ---- store Z node-major interleaved, permuted row order ----
        if (valid) {
            #pragma unroll
            for (int r = 0; r < 4; ++r) {
                int rr = 4 * g + r;
                int db = rr >> 3, dn = n8 + (rr & 7);
                unsigned zw[4];
                #pragma unroll
                for (int tt = 0; tt < 4; ++tt)
                    zw[tt] = cvt_pk(acc2[2 * tt][r], acc2[2 * tt + 1][r]);
                *(uint4*)(Z + ((size_t)dn * 2 + db) * CC + c * 8) = *(uint4*)zw;
            }
        }
    }
}

// ---------------- K2: aggregate(Z) + b2 + BN2 + GELU2 -> a2 (standard order) ----------------
// TWO nodes per wave (one per 32-lane half) -- no duplicated epilogue work.
__global__ __launch_bounds__(256) void k_agg_bn(
    const u16* __restrict__ Zin, const int* __restrict__ off, const int2* __restrict__ eg,
    const float* __restrict__ b2, const float* __restrict__ g2, const float* __restrict__ be2,
    u16* __restrict__ A2, int N)
{
    __shared__ u16 TW[4][2][256];
    const int wv = threadIdx.x >> 6;
    const int l = threadIdx.x & 63;
    const int half = l >> 5;
    const int h = l & 31;
    const int b = h >> 4;
    const int c = h & 15;
    const int n = blockIdx.x * 8 + wv * 2 + half;
    const bool nv = n < N;
    const int nn = nv ? n : 0;
    const u16* Ab = Zin + b * CC + c * 8;

    float bb[8];
    #pragma unroll
    for (int t = 0; t < 8; ++t) bb[t] = b2[t * 16 + c];

    int s = off[nn];
    int e = nv ? off[nn + 1] : 0;
    float a[8] = {0.f, 0.f, 0.f, 0.f, 0.f, 0.f, 0.f, 0.f};
    for (int j = s; j < e; j += 4) {
        int2 e0 = eg[j], e1 = eg[j + 1], e2 = eg[j + 2], e3 = eg[j + 3];
        int s0 = e0.x;                  float w0 = __int_as_float(e0.y);
        int s1 = (j + 1 < e) ? e1.x : 0; float w1 = (j + 1 < e) ? __int_as_float(e1.y) : 0.f;
        int s2 = (j + 2 < e) ? e2.x : 0; float w2 = (j + 2 < e) ? __int_as_float(e2.y) : 0.f;
        int s3 = (j + 3 < e) ? e3.x : 0; float w3 = (j + 3 < e) ? __int_as_float(e3.y) : 0.f;
        bf16x8 v0 = *(const bf16x8*)(Ab + (size_t)s0 * 256);
        bf16x8 v1 = *(const bf16x8*)(Ab + (size_t)s1 * 256);
        bf16x8 v2 = *(const bf16x8*)(Ab + (size_t)s2 * 256);
        bf16x8 v3 = *(const bf16x8*)(Ab + (size_t)s3 * 256);
        #pragma unroll
        for (int q = 0; q < 8; ++q) {
            a[q] = fmaf(w0, bf2f((u16)v0[q]), a[q]);
            a[q] = fmaf(w1, bf2f((u16)v1[q]), a[q]);
            a[q] = fmaf(w2, bf2f((u16)v2[q]), a[q]);
            a[q] = fmaf(w3, bf2f((u16)v3[q]), a[q]);
        }
    }

    // + b2, BN2 stats over this half's 32 lanes x 8 values = 256
    float ss = 0.f, qq = 0.f;
    #pragma unroll
    for (int t = 0; t < 8; ++t) {
        float hh = a[t] + bb[t];
        a[t] = hh;
        ss += hh;
        qq += hh * hh;
    }
    #pragma unroll
    for (int d = 1; d < 32; d <<= 1) {   // masks 1..16: stays within the 32-lane half
        ss += __shfl_xor(ss, d);
        qq += __shfl_xor(qq, d);
    }
    float mean = ss * (1.f / 256.f);
    float var  = qq * (1.f / 256.f) - mean * mean;
    float sc = g2[nn] * rsqrtf(fmaxf(var, 0.f) + 1e-5f);
    float sh = be2[nn] - mean * sc;

    // GELU + un-permute via LDS (channel t*16+c <- permuted slot), coalesced store
    #pragma unroll
    for (int t = 0; t < 8; ++t)
        TW[wv][half][b * CC + t * 16 + c] = f2bf(gelu_f(a[t] * sc + sh));
    // wave-synchronous LDS write->read (compiler orders via lgkmcnt)
    if (nv) {
        bf16x8 v = *(const bf16x8*)&TW[wv][half][h * 8];
        *(bf16x8*)(A2 + (size_t)nn * 256 + h * 8) = v;
    }
}

// ---------------- K3: aggregate(a2) -> standard-layout f32 output ----------------
// TWO nodes per wave; gathers contiguous 512B/edge; stores 32B/lane coalesced.
__global__ __launch_bounds__(256) void k_agg_out(
    const u16* __restrict__ A2, const int* __restrict__ off, const int2* __restrict__ eg,
    float* __restrict__ Out, int N)
{
    const int wv = threadIdx.x >> 6;
    const int l = threadIdx.x & 63;
    const int half = l >> 5;
    const int h = l & 31;
    const int b = h >> 4;
    const int c = h & 15;
    const int n = blockIdx.x * 8 + wv * 2 + half;
    const bool nv = n < N;
    const int nn = nv ? n : 0;
    const u16* Ab = A2 + h * 8;

    int s = off[nn];
    int e = nv ? off[nn + 1] : 0;
    float a[8] = {0.f, 0.f, 0.f, 0.f, 0.f, 0.f, 0.f, 0.f};
    for (int j = s; j < e; j += 4) {
        int2 e0 = eg[j], e1 = eg[j + 1], e2 = eg[j + 2], e3 = eg[j + 3];
        int s0 = e0.x;                  float w0 = __int_as_float(e0.y);
        int s1 = (j + 1 < e) ? e1.x : 0; float w1 = (j + 1 < e) ? __int_as_float(e1.y) : 0.f;
        int s2 = (j + 2 < e) ? e2.x : 0; float w2 = (j + 2 < e) ? __int_as_float(e2.y) : 0.f;
        int s3 = (j + 3 < e) ? e3.x : 0; float w3 = (j + 3 < e) ? __int_as_float(e3.y) : 0.f;
        bf16x8 v0 = *(const bf16x8*)(Ab + (size_t)s0 * 256);
        bf16x8 v1 = *(const bf16x8*)(Ab + (size_t)s1 * 256);
        bf16x8 v2 = *(const bf16x8*)(Ab + (size_t)s2 * 256);
        bf16x8 v3 = *(const bf16x8*)(Ab + (size_t)s3 * 256);
        #pragma unroll
        for (int q = 0; q < 8; ++q) {
            a[q] = fmaf(w0, bf2f((u16)v0[q]), a[q]);
            a[q] = fmaf(w1, bf2f((u16)v1[q]), a[q]);
            a[q] = fmaf(w2, bf2f((u16)v2[q]), a[q]);
            a[q] = fmaf(w3, bf2f((u16)v3[q]), a[q]);
        }
    }
    if (nv) {
        float* d = Out + ((size_t)b * N + nn) * CC + c * 8;
        *(float4*)&d[0] = make_float4(a[0], a[1], a[2], a[3]);
        *(float4*)&d[4] = make_float4(a[4], a[5], a[6], a[7]);
    }
}

// ---------------- launch ----------------

extern "C" void kernel_launch(void* const* d_in, const int* in_sizes, int n_in,
                              void* d_out, int out_size, void* d_ws, size_t ws_size,
                              hipStream_t stream)
{
    const float* x   = (const float*)d_in[0];
    const int*   ei  = (const int*)d_in[1];
    const float* nrm = (const float*)d_in[2];
    const float* W1  = (const float*)d_in[3];
    const float* b1  = (const float*)d_in[4];
    const float* g1  = (const float*)d_in[5];
    const float* be1 = (const float*)d_in[6];
    const float* W2  = (const float*)d_in[7];
    const float* b2  = (const float*)d_in[8];
    const float* g2  = (const float*)d_in[9];
    const float* be2 = (const float*)d_in[10];

    const int N = in_sizes[5];   // g1 has N elements
    const int E = in_sizes[2];   // norm has E elements
    const int* row = ei;         // edge_index[0] = scatter dst
    const int* col = ei + E;     // edge_index[1] = gather src
    const int nb = (N + 1023) / 1024;

    auto al = [](size_t v) { return (v + 255) & ~(size_t)255; };
    char* p = (char*)d_ws;
    int* off    = (int*)p;   p += al((size_t)(N + 1) * 4);
    int* cur    = (int*)p;   p += al((size_t)N * 4);
    int2* eg    = (int2*)p;  p += al((size_t)(E + 8) * 8);   // +8 pad: tail-slot overreads
    int* bsum   = (int*)p;   p += al((size_t)nb * 4);
    int* boff   = (int*)p;   p += al((size_t)nb * 4);
    u16* Wp1    = (u16*)p;   p += al((size_t)CC * CC * 2);
    u16* Wp2    = (u16*)p;   p += al((size_t)CC * CC * 2);
    u16* Zbuf   = (u16*)p;   p += al((size_t)2 * N * CC * 2);
    u16* A2buf  = (u16*)p;   p += al((size_t)2 * N * CC * 2);

    // prep (zero cur + both W repacks) then CSR by destination
    const int prep_n = N + 2 * CC * CC;
    k_prep<<<(prep_n + 255) / 256, 256, 0, stream>>>(cur, N, W1, Wp1, W2, Wp2);
    k_hist<<<(E + 255) / 256, 256, 0, stream>>>(row, cur, E);
    k_scan_a<<<nb, 256, 0, stream>>>(cur, bsum, N);
    k_scan_b<<<1, 64, 0, stream>>>(bsum, boff, off, N, nb);
    k_scan_c<<<nb, 256, 0, stream>>>(cur, boff, off, N);   // also zeroes cur
    k_fill<<<(E + 255) / 256, 256, 0, stream>>>(row, col, nrm, off, cur, eg, E);

    const int ga = (N + 7) / 8;
    // K1: persistent fused GEMM1+BN1+GELU1+GEMM2 -> Z
    k_fused_l1<<<512, 256, 0, stream>>>(x, Wp1, Wp2, b1, g1, be1, Zbuf, N);
    // K2: aggregate + b2 + BN2 + GELU2 -> a2 (node-major, standard channel order)
    k_agg_bn<<<ga, 256, 0, stream>>>(Zbuf, off, eg, b2, g2, be2, A2buf, N);
    // K3: aggregate -> standard f32 out (coalesced)
    k_agg_out<<<ga, 256, 0, stream>>>(A2buf, off, eg, (float*)d_out, N);
}